// Round 17
// baseline (188.288 us; speedup 1.0000x reference)
//
#include <hip/hip_runtime.h>
#include <hip/hip_bf16.h>
#include <cstddef>

#define H 16
#define DN 128
#define DR 64
#define DV 128
#define QLR 1536
#define KVLR 512
#define HID 2048
#define SLEN 2048
#define EPS 1e-6f
#define SCALE 0.08838834764831845f   /* 1/sqrt(128) */
#define QK_SCALE (0.08838834764831845f * 1.4426950408889634f)  /* SCALE * log2(e) */

typedef __attribute__((ext_vector_type(8))) short short8;
typedef __attribute__((ext_vector_type(4))) float f32x4;
typedef unsigned short u16;

__device__ __forceinline__ u16 f2bf(float f) {
    __hip_bfloat16 h = __float2bfloat16(f);
    return __builtin_bit_cast(u16, h);
}
__device__ __forceinline__ float b2f(u16 v) {
    return __bfloat162float(__builtin_bit_cast(__hip_bfloat16, v));
}
__device__ __forceinline__ unsigned pack2(float a, float b) {
    return (unsigned)f2bf(a) | ((unsigned)f2bf(b) << 16);
}

// ---------------- shared transpose-cast block: W f32 [K][N] tile -> Wt bf16 [Npad][K] ----------------
__device__ __forceinline__ void tcast_block(
    const float* __restrict__ W, u16* __restrict__ Wt,
    int K, int N, int nx, float scale, int b, float (*T)[65])
{
    const int tid = threadIdx.x;
    const int bx = b % nx, by = b / nx;
    const int n0 = bx * 64, k0 = by * 64;
    const bool inb = (n0 < N);
    {
        int r = tid >> 4, c4 = (tid & 15) * 4;
        #pragma unroll
        for (int rr = 0; rr < 4; ++rr) {
            int row = rr * 16 + r;
            float4 v = inb ? *reinterpret_cast<const float4*>(W + (size_t)(k0 + row) * N + n0 + c4)
                           : make_float4(0.f, 0.f, 0.f, 0.f);
            T[row][c4] = v.x * scale; T[row][c4 + 1] = v.y * scale;
            T[row][c4 + 2] = v.z * scale; T[row][c4 + 3] = v.w * scale;
        }
    }
    __syncthreads();
    {
        int n = tid >> 2, kq = (tid & 3) * 16;
        unsigned u[8];
        #pragma unroll
        for (int jj = 0; jj < 8; ++jj)
            u[jj] = pack2(T[kq + 2 * jj][n], T[kq + 2 * jj + 1][n]);
        u16* dst = Wt + (size_t)(n0 + n) * K + k0 + kq;
        *reinterpret_cast<uint4*>(dst)     = make_uint4(u[0], u[1], u[2], u[3]);
        *reinterpret_cast<uint4*>(dst + 8) = make_uint4(u[4], u[5], u[6], u[7]);
    }
}

// ---------------- prep: x cast (blocks 0..2047) + Wqd/Wkvd transpose-casts ----------------
__global__ __launch_bounds__(256) void prep_all(
    const float* __restrict__ x, u16* __restrict__ xb,
    const float* __restrict__ Wqd, const float* __restrict__ Wkvd,
    u16* __restrict__ BtF)
{
    const int tid = threadIdx.x;
    if (blockIdx.x < 2048) {
        size_t base = ((size_t)blockIdx.x * 256 + tid) * 8;
        float4 v0 = *reinterpret_cast<const float4*>(x + base);
        float4 v1 = *reinterpret_cast<const float4*>(x + base + 4);
        union { short8 s; unsigned u[4]; } p;
        p.u[0] = pack2(v0.x, v0.y); p.u[1] = pack2(v0.z, v0.w);
        p.u[2] = pack2(v1.x, v1.y); p.u[3] = pack2(v1.z, v1.w);
        *reinterpret_cast<short8*>(xb + base) = p.s;
        return;
    }
    __shared__ float T[64][65];
    int b = blockIdx.x - 2048;
    if (b < 768) tcast_block(Wqd, BtF, 2048, 1536, 24, 1.0f, b, T);
    else         tcast_block(Wkvd, BtF + (size_t)1536 * 2048, 2048, 576, 10, 1.0f, b - 768, T);
}

// ---------------- unified GEMM core: BM=64, BN=128, BK=64 (48KB double-buffered LDS) ----------------
__device__ __forceinline__ void stage6(const char* const* gb, const unsigned* srcOff,
                                       const int* ldsBase, u16* smemBuf, unsigned koff)
{
    #pragma unroll
    for (int j = 0; j < 6; ++j)
        __builtin_amdgcn_global_load_lds(
            (const __attribute__((address_space(1))) unsigned int*)(gb[j] + srcOff[j] + koff),
            (__attribute__((address_space(3))) unsigned int*)(smemBuf + ldsBase[j]),
            16, 0, 0);
}

template<bool BF16OUT>
__device__ __forceinline__ void gemm_core64(
    const u16* __restrict__ A, const u16* __restrict__ Bt, void* __restrict__ Cv,
    int N, int K, int m0, int n0, u16 (*smem)[12288])
{
    const int tid = threadIdx.x, lane = tid & 63, w = tid >> 6;
    const int colk = lane & 15, grp16 = (lane >> 4) * 16;
    const size_t Kb = (size_t)K * 2;

    const char* gb[6];
    unsigned srcOff[6];
    int ldsBase[6];
    #pragma unroll
    for (int j = 0; j < 6; ++j) {
        int c = w * 6 + j;
        bool isA = (c < 8);
        int cc = isA ? c : c - 8;
        int o = cc * 1024 + lane * 16;
        int u = o ^ (((o >> 7) & 7) << 4);
        int row = u >> 7, kbyte = u & 127;
        gb[j] = isA ? (const char*)A : (const char*)Bt;
        srcOff[j] = (unsigned)((size_t)(isA ? m0 + row : n0 + row) * Kb + kbyte);
        ldsBase[j] = isA ? cc * 512 : 4096 + cc * 512;
    }

    const int wc = w * 32;
    int aoff[8], boff[4];
    #pragma unroll
    for (int ks = 0; ks < 2; ++ks) {
        #pragma unroll
        for (int i = 0; i < 4; ++i) {
            int ra = i * 16 + colk;
            int oa = ra * 128 + ks * 64 + grp16;
            aoff[ks * 4 + i] = oa ^ ((ra & 7) << 4);
        }
        #pragma unroll
        for (int jj = 0; jj < 2; ++jj) {
            int rb = wc + jj * 16 + colk;
            int ob = rb * 128 + ks * 64 + grp16;
            boff[ks * 2 + jj] = (ob ^ ((rb & 7) << 4)) + 8192;
        }
    }

    f32x4 acc[4][2];
    #pragma unroll
    for (int i = 0; i < 4; ++i)
        #pragma unroll
        for (int j = 0; j < 2; ++j) acc[i][j] = (f32x4){0.f, 0.f, 0.f, 0.f};

    const int NT = K >> 6;
    stage6(gb, srcOff, ldsBase, &smem[0][0], 0);
    __syncthreads();
    int cur = 0;
    for (int t = 0; t < NT; ++t) {
        if (t + 1 < NT) stage6(gb, srcOff, ldsBase, &smem[cur ^ 1][0], (unsigned)(t + 1) * 128);
        const char* base = (const char*)&smem[cur][0];
        #pragma unroll
        for (int ks = 0; ks < 2; ++ks) {
            short8 af[4], bfr[2];
            #pragma unroll
            for (int i = 0; i < 4; ++i) af[i] = *reinterpret_cast<const short8*>(base + aoff[ks * 4 + i]);
            #pragma unroll
            for (int jj = 0; jj < 2; ++jj) bfr[jj] = *reinterpret_cast<const short8*>(base + boff[ks * 2 + jj]);
            __builtin_amdgcn_s_setprio(1);
            #pragma unroll
            for (int i = 0; i < 4; ++i)
                #pragma unroll
                for (int jj = 0; jj < 2; ++jj)
                    acc[i][jj] = __builtin_amdgcn_mfma_f32_16x16x32_bf16(af[i], bfr[jj], acc[i][jj], 0, 0, 0);
            __builtin_amdgcn_s_setprio(0);
        }
        __syncthreads();
        cur ^= 1;
    }

    #pragma unroll
    for (int i = 0; i < 4; ++i) {
        int grow0 = m0 + i * 16 + (grp16 >> 2);
        #pragma unroll
        for (int jj = 0; jj < 2; ++jj) {
            int gcol = n0 + wc + jj * 16 + colk;
            if (gcol < N) {
                #pragma unroll
                for (int r = 0; r < 4; ++r) {
                    float v2 = acc[i][jj][r];
                    if (BF16OUT) ((u16*)Cv)[(size_t)(grow0 + r) * N + gcol] = f2bf(v2);
                    else         ((float*)Cv)[(size_t)(grow0 + r) * N + gcol] = v2;
                }
            }
        }
    }
}

__device__ __forceinline__ void xcd_map(int orig, int nwg, int nby, int& bx, int& by)
{
    int xcd = orig & 7, o8 = orig >> 3;
    int qq = nwg >> 3, rr = nwg & 7;
    int v = (xcd < rr ? xcd * (qq + 1) : rr * (qq + 1) + (xcd - rr) * qq) + o8;
    bx = v / nby; by = v - bx * nby;
}

// down-GEMM (blocks 0..543) + Wqu/Wkvu/Wo transpose-casts (blocks 544..3231)
__global__ __launch_bounds__(256) void gemm_down_fused(
    const u16* __restrict__ xb, const u16* __restrict__ BtF, float* __restrict__ fC,
    const float* __restrict__ Wqu, const float* __restrict__ Wkvu, const float* __restrict__ Wo,
    u16* __restrict__ Wqu_t, u16* __restrict__ Wkvu_t, u16* __restrict__ Wo_t)
{
    __shared__ u16 smem[2][12288];   // 48 KB
    if (blockIdx.x < 544) {
        int bx, by;
        xcd_map(blockIdx.x, 544, 32, bx, by);
        gemm_core64<false>(xb, BtF, fC, 2112, 2048, by * 64, bx * 128, smem);
        return;
    }
    float (*T)[65] = reinterpret_cast<float(*)[65]>(&smem[0][0]);
    int b = blockIdx.x - 544;
    if (b < 1152)      tcast_block(Wqu,  Wqu_t,  1536, 3072, 48, QK_SCALE, b, T);
    else if (b < 1664) tcast_block(Wkvu, Wkvu_t, 512,  4096, 64, 1.0f, b - 1152, T);
    else               tcast_block(Wo,   Wo_t,   2048, 2048, 32, 1.0f, b - 1664, T);
}

// q_up (blocks 0..767) + kv_up (blocks 768..1791) in one launch
__global__ __launch_bounds__(256) void gemm_dual(
    const u16* __restrict__ Aq, const u16* __restrict__ Bq, u16* __restrict__ Cq,
    const u16* __restrict__ Ak, const u16* __restrict__ Bk, u16* __restrict__ Ck)
{
    __shared__ u16 smem[2][12288];
    int b = blockIdx.x;
    const u16 *A, *Bt; u16* C; int N, K, nwg;
    if (b < 768) { A = Aq; Bt = Bq; C = Cq; N = 3072; K = 1536; nwg = 768; }
    else { b -= 768; A = Ak; Bt = Bk; C = Ck; N = 4096; K = 512; nwg = 1024; }
    int bx, by;
    xcd_map(b, nwg, 32, bx, by);
    gemm_core64<true>(A, Bt, C, N, K, by * 64, bx * 128, smem);
}

// Wo GEMM: 512 blocks (16 x 32), fp32 out
__global__ __launch_bounds__(256) void gemm_wo(
    const u16* __restrict__ A, const u16* __restrict__ Bt, float* __restrict__ C)
{
    __shared__ u16 smem[2][12288];
    int bx, by;
    xcd_map(blockIdx.x, 512, 32, bx, by);
    gemm_core64<false>(A, Bt, C, 2048, 2048, by * 64, bx * 128, smem);
}

// ---------------- fused double RMSNorm: fC rows -> qdb (1536) + ckvb (512) ----------------
__global__ __launch_bounds__(256) void rmsnorm2_bf16(
    const float* __restrict__ fC, const float* __restrict__ qw,
    const float* __restrict__ kvw, u16* __restrict__ qdb, u16* __restrict__ ckvb)
{
    const int row = blockIdx.x, tid = threadIdx.x;
    const float* p = fC + (size_t)row * 2112;
    float ssq = 0.f, ssk = 0.f;
    for (int i = tid * 4; i < 1536; i += 1024) {
        float4 v = *reinterpret_cast<const float4*>(p + i);
        ssq += v.x * v.x + v.y * v.y + v.z * v.z + v.w * v.w;
    }
    if (tid < 128) {
        float4 v = *reinterpret_cast<const float4*>(p + 1536 + tid * 4);
        ssk = v.x * v.x + v.y * v.y + v.z * v.z + v.w * v.w;
    }
    __shared__ float wsq[4], wsk[4];
    int lane = tid & 63, wv = tid >> 6;
    #pragma unroll
    for (int off = 32; off; off >>= 1) {
        ssq += __shfl_down(ssq, off);
        ssk += __shfl_down(ssk, off);
    }
    if (lane == 0) { wsq[wv] = ssq; wsk[wv] = ssk; }
    __syncthreads();
    if (tid == 0) {
        wsq[0] = rsqrtf((wsq[0] + wsq[1] + wsq[2] + wsq[3]) / 1536.f + EPS);
        wsk[0] = rsqrtf((wsk[0] + wsk[1] + wsk[2] + wsk[3]) / 512.f + EPS);
    }
    __syncthreads();
    float scq = wsq[0], sck = wsk[0];
    for (int i = tid * 4; i < 1536; i += 1024) {
        float4 v = *reinterpret_cast<const float4*>(p + i);
        float4 g = *reinterpret_cast<const float4*>(qw + i);
        *reinterpret_cast<uint2*>(qdb + (size_t)row * 1536 + i) =
            make_uint2(pack2(v.x * scq * g.x, v.y * scq * g.y),
                       pack2(v.z * scq * g.z, v.w * scq * g.w));
    }
    if (tid < 128) {
        int i = tid * 4;
        float4 v = *reinterpret_cast<const float4*>(p + 1536 + i);
        float4 g = *reinterpret_cast<const float4*>(kvw + i);
        *reinterpret_cast<uint2*>(ckvb + (size_t)row * 512 + i) =
            make_uint2(pack2(v.x * sck * g.x, v.y * sck * g.y),
                       pack2(v.z * sck * g.z, v.w * sck * g.w));
    }
}

// ---------------- merged: RoPE (blocks 0..2047) + V transpose (blocks 2048..3071) ----------------
__global__ __launch_bounds__(256) void rope_vtrans(
    u16* __restrict__ q, const float* __restrict__ krsrc, int krStride,
    u16* __restrict__ krot, const u16* __restrict__ kvbf, u16* __restrict__ vtb)
{
    const int tid = threadIdx.x;
    if (blockIdx.x < 2048) {
        const int s = blockIdx.x;
        __shared__ float cs[32], sn[32];
        if (tid < 32) {
            float inv = powf(10000.0f, -(float)tid / 32.0f);
            float ang = (float)s * inv;
            cs[tid] = cosf(ang); sn[tid] = sinf(ang);
        }
        __syncthreads();
        float ev[2], ov[2]; int hh[2], ii[2];
        #pragma unroll
        for (int it = 0; it < 2; ++it) {
            int pidx = tid + it * 256;
            int h = pidx >> 5, i = pidx & 31;
            hh[it] = h; ii[it] = i;
            const u16* base = q + (size_t)s * 3072 + h * 192 + 128;
            ev[it] = b2f(base[2 * i]); ov[it] = b2f(base[2 * i + 1]);
        }
        __syncthreads();
        #pragma unroll
        for (int it = 0; it < 2; ++it) {
            int h = hh[it], i = ii[it];
            u16* base = q + (size_t)s * 3072 + h * 192 + 128;
            base[i]      = f2bf(ev[it] * cs[i] - ov[it] * sn[i]);
            base[32 + i] = f2bf(ov[it] * cs[i] + ev[it] * sn[i]);
        }
        if (tid < 32) {
            int i = tid;
            float e = krsrc[(size_t)s * krStride + 2 * i];
            float o = krsrc[(size_t)s * krStride + 2 * i + 1];
            krot[(size_t)s * 64 + i]      = f2bf(e * cs[i] - o * sn[i]);
            krot[(size_t)s * 64 + 32 + i] = f2bf(o * cs[i] + e * sn[i]);
        }
        return;
    }
    const int bid = blockIdx.x - 2048;     // 1024 = 16 h x 32 s-tiles x 2 d-tiles
    const int h = bid & 15, rem = bid >> 4;
    const int st = rem & 31, dt = rem >> 5;
    __shared__ u16 T[64][72];
    #pragma unroll
    for (int it = 0; it < 2; ++it) {
        int c = it * 256 + tid;
        int r = c >> 3, c8 = (c & 7) * 8;
        short8 v = *reinterpret_cast<const short8*>(
            kvbf + ((size_t)(st * 64 + r) * 16 + h) * 256 + 128 + dt * 64 + c8);
        *reinterpret_cast<short8*>(&T[r][c8]) = v;
    }
    __syncthreads();
    #pragma unroll
    for (int it = 0; it < 2; ++it) {
        int c = it * 256 + tid;
        int d = c >> 3, s8 = (c & 7) * 8;
        union { short8 s; u16 e[8]; } o;
        #pragma unroll
        for (int j = 0; j < 8; ++j) o.e[j] = T[s8 + j][d];
        *reinterpret_cast<short8*>(
            vtb + ((size_t)(h * 128 + dt * 64 + d)) * 2048 + st * 64 + s8) = o.s;
    }
}

// ---------------- split-K flash attention: KB=32, gload_lds dbuf, counted vmcnt + raw barriers ----------------
// Loop: issue(t+1) -> vmcnt(5) [tile t's own loads only] -> s_barrier -> compute(t) -> s_barrier.
// Next tile's loads stay in flight across barriers (never drained to 0 in steady state).
__global__ __launch_bounds__(256, 2) void attn_chunk(
    const u16* __restrict__ qbf,   // [S][H][192]
    const u16* __restrict__ kvbf,  // [S][H][256]  (k_nope | v)
    const u16* __restrict__ krot,  // [S][64]
    const u16* __restrict__ vtb,   // [H][128][2048]  V^T
    u16* __restrict__ outb,        // [S][2048]
    u16* __restrict__ partAcc,     // [1152][64][128] bf16
    float* __restrict__ partML)    // [1152][64][2]
{
    const int bid = blockIdx.x;
    const int xcd = bid & 7, slot = bid >> 3;       // slot 0..159
    const int h = xcd + 8 * (slot & 1);             // interleave heads
    const int r80 = 79 - (slot >> 1);               // big chunks first
    int qb, ch, S, poff;
    if (r80 < 8)       { qb = r80;                 ch = 0;      S = 1; poff = 0; }
    else if (r80 < 24) { int u = r80 - 8;  qb = 8 + (u >> 1);  ch = u & 1; S = 2; poff = (qb - 8) * 2 + ch; }
    else if (r80 < 48) { int u = r80 - 24; qb = 16 + u / 3;    ch = u % 3; S = 3; poff = 16 + (qb - 16) * 3 + ch; }
    else               { int u = r80 - 48; qb = 24 + (u >> 2); ch = u & 3; S = 4; poff = 40 + (qb - 24) * 4 + ch; }
    const int s0 = qb * 64;
    const int nt32 = 2 * qb + 2;                    // 32-key tiles total
    const int t0 = ch * 16;
    const int t1 = (t0 + 16 < nt32) ? (t0 + 16) : nt32;
    const int slotId = h * 72 + poff;
    const int tid = threadIdx.x, lane = tid & 63, w = tid >> 6;
    const int colk = lane & 15, grp = lane >> 4, g8 = grp * 8;

    // per buffer: [Ks 32x192 u16 = 6144][Vt 128x32 u16 = 4096] = 10240 u16 (20KB)
    __shared__ u16 smem[2][10240];

    const int qg = s0 + w * 16 + colk;

    short8 qreg[6];
    {
        const u16* qp = qbf + ((size_t)qg * H + h) * 192;
        #pragma unroll
        for (int ks = 0; ks < 6; ++ks)
            qreg[ks] = *reinterpret_cast<const short8*>(qp + ks * 32 + g8);
    }

    // staging: 20 chunks of 1KB (Ks 0..11, Vt 12..19); wave w owns chunks 5w..5w+4.
    const char* gbase[5];
    unsigned curOff[5], strideB[5];
    int ldsOff[5];
    #pragma unroll
    for (int j = 0; j < 5; ++j) {
        int c = w * 5 + j;
        if (c < 12) {
            int o = c * 1024 + lane * 16;           // byte within Ks region
            int row = o / 384, rem = o % 384, s = rem >> 4;
            int kslot = (s & 24) | ((s ^ row) & 7);
            if (kslot < 16) {
                gbase[j] = (const char*)(kvbf + h * 256);
                curOff[j] = (unsigned)((row * 4096 + kslot * 8) * 2);
                strideB[j] = 32 * 4096 * 2;
            } else {
                gbase[j] = (const char*)krot;
                curOff[j] = (unsigned)((row * 64 + (kslot - 16) * 8) * 2);
                strideB[j] = 32 * 64 * 2;
            }
            ldsOff[j] = c * 512;
        } else {
            int cc = c - 12;
            int o = cc * 1024 + lane * 16;          // byte within Vt region
            int row = o >> 6, s = (o & 63) >> 4;    // row = d (0..127), 4 slots
            int vks = (s ^ row ^ (row >> 2)) & 3;
            gbase[j] = (const char*)(vtb + (size_t)h * 128 * 2048);
            curOff[j] = (unsigned)((row * 2048 + vks * 8) * 2);
            strideB[j] = 32 * 2;
            ldsOff[j] = 6144 + cc * 512;
        }
        curOff[j] += (unsigned)t0 * strideB[j];
    }

    float m_run = -1e30f, l_run = 0.f;
    f32x4 acc_o[8];
    #pragma unroll
    for (int i = 0; i < 8; ++i) acc_o[i] = (f32x4){0.f, 0.f, 0.f, 0.f};

    const int srcA = colk + ((grp & 1) << 5);
    const int srcB = srcA + 16;
    const bool hiSel = (grp >> 1) != 0;

    // prologue: stage tile t0 into buffer 0, flush everything once
    #pragma unroll
    for (int j = 0; j < 5; ++j) {
        __builtin_amdgcn_global_load_lds(
            (const __attribute__((address_space(1))) unsigned int*)(gbase[j] + curOff[j]),
            (__attribute__((address_space(3))) unsigned int*)(&smem[0][0] + ldsOff[j]),
            16, 0, 0);
        curOff[j] += strideB[j];
    }
    asm volatile("s_waitcnt vmcnt(0)" ::: "memory");
    __builtin_amdgcn_sched_barrier(0);
    __builtin_amdgcn_s_barrier();

    int buf = 0;
    for (int t = t0; t < t1; ++t) {
        if (t + 1 < t1) {
            u16* dst = &smem[buf ^ 1][0];
            #pragma unroll
            for (int j = 0; j < 5; ++j) {
                __builtin_amdgcn_global_load_lds(
                    (const __attribute__((address_space(1))) unsigned int*)(gbase[j] + curOff[j]),
                    (__attribute__((address_space(3))) unsigned int*)(dst + ldsOff[j]),
                    16, 0, 0);
                curOff[j] += strideB[j];
            }
            asm volatile("s_waitcnt vmcnt(5)" ::: "memory");   // tile t's own 5 loads done
        } else {
            asm volatile("s_waitcnt vmcnt(0)" ::: "memory");   // last tile: drain
        }
        __builtin_amdgcn_sched_barrier(0);
        __builtin_amdgcn_s_barrier();       // all waves' tile-t loads in LDS

        const u16* KsB = &smem[buf][0];
        const u16* VtB = &smem[buf][6144];

        // swapped QK^T: sacc[ct][r] = S[key = t*32 + ct*16 + 4*grp + r][q = colk]
        f32x4 sacc[2];
        sacc[0] = (f32x4){0.f, 0.f, 0.f, 0.f};
        sacc[1] = (f32x4){0.f, 0.f, 0.f, 0.f};
        __builtin_amdgcn_s_setprio(1);
        #pragma unroll
        for (int ks = 0; ks < 6; ++ks) {
            #pragma unroll
            for (int ct = 0; ct < 2; ++ct) {
                int key = ct * 16 + colk;
                int slotIdx = ks * 4 + grp;
                int sl = (slotIdx & 24) | ((slotIdx ^ key) & 7);
                short8 kf = *reinterpret_cast<const short8*>(&KsB[key * 192 + sl * 8]);
                sacc[ct] = __builtin_amdgcn_mfma_f32_16x16x32_bf16(kf, qreg[ks], sacc[ct], 0, 0, 0);
            }
        }
        __builtin_amdgcn_s_setprio(0);

        // causal mask (only tiles overlapping the diagonal)
        if (t >= 2 * qb) {
            #pragma unroll
            for (int ct = 0; ct < 2; ++ct) {
                int keyb = t * 32 + ct * 16 + 4 * grp;
                #pragma unroll
                for (int r = 0; r < 4; ++r)
                    if (keyb + r > qg) sacc[ct][r] = -1e30f;
            }
        }

        // in-lane row max over 8, gated rescale
        float lmax = fmaxf(fmaxf(fmaxf(sacc[0][0], sacc[0][1]), fmaxf(sacc[0][2], sacc[0][3])),
                           fmaxf(fmaxf(sacc[1][0], sacc[1][1]), fmaxf(sacc[1][2], sacc[1][3])));
        bool need = lmax > m_run + 11.5f;
        if (__any((int)need)) {
            float mx = fmaxf(m_run, lmax);
            mx = fmaxf(mx, __shfl_xor(mx, 16));
            mx = fmaxf(mx, __shfl_xor(mx, 32));
            float f = exp2f(m_run - mx);
            m_run = mx;
            l_run *= f;
            #pragma unroll
            for (int i = 0; i < 8; ++i) {
                acc_o[i][0] *= f; acc_o[i][1] *= f;
                acc_o[i][2] *= f; acc_o[i][3] *= f;
            }
        }

        // P = exp2(S - m), packed bf16 pairs
        unsigned pku[4];
        float psum = 0.f;
        #pragma unroll
        for (int ct = 0; ct < 2; ++ct) {
            float p0 = exp2f(sacc[ct][0] - m_run);
            float p1 = exp2f(sacc[ct][1] - m_run);
            float p2 = exp2f(sacc[ct][2] - m_run);
            float p3 = exp2f(sacc[ct][3] - m_run);
            psum += (p0 + p1) + (p2 + p3);
            pku[ct * 2]     = pack2(p0, p1);
            pku[ct * 2 + 1] = pack2(p2, p3);
        }
        l_run += psum;

        // swapped PV: b-frag of P^T via 4-lane-group shuffles
        unsigned a0 = __shfl(pku[0], srcA);
        unsigned a1 = __shfl(pku[1], srcA);
        unsigned a2 = __shfl(pku[0], srcB);
        unsigned a3 = __shfl(pku[1], srcB);
        unsigned b0 = __shfl(pku[2], srcA);
        unsigned b1 = __shfl(pku[3], srcA);
        unsigned b2 = __shfl(pku[2], srcB);
        unsigned b3 = __shfl(pku[3], srcB);
        union { short8 s; unsigned u[4]; } bq;
        bq.u[0] = hiSel ? b0 : a0;
        bq.u[1] = hiSel ? b1 : a1;
        bq.u[2] = hiSel ? b2 : a2;
        bq.u[3] = hiSel ? b3 : a3;
        __builtin_amdgcn_s_setprio(1);
        #pragma unroll
        for (int ct = 0; ct < 8; ++ct) {
            int cc = ct * 16 + colk;
            int vsl = (grp ^ cc ^ (cc >> 2)) & 3;
            short8 vb = *reinterpret_cast<const short8*>(&VtB[cc * 32 + vsl * 8]);
            acc_o[ct] = __builtin_amdgcn_mfma_f32_16x16x32_bf16(vb, bq.s, acc_o[ct], 0, 0, 0);
        }
        __builtin_amdgcn_s_setprio(0);

        __builtin_amdgcn_s_barrier();       // all waves done reading buf; next iter may overwrite
        buf ^= 1;
    }

    float l = l_run;
    l += __shfl_xor(l, 16);
    l += __shfl_xor(l, 32);
    const int rloc = w * 16 + colk;
    if (S == 1) {
        float invl = 1.0f / l;
        u16* orow = outb + (size_t)qg * 2048 + h * 128 + 4 * grp;
        #pragma unroll
        for (int ct = 0; ct < 8; ++ct) {
            uint2 pk;
            pk.x = pack2(acc_o[ct][0] * invl, acc_o[ct][1] * invl);
            pk.y = pack2(acc_o[ct][2] * invl, acc_o[ct][3] * invl);
            *reinterpret_cast<uint2*>(orow + ct * 16) = pk;
        }
    } else {
        if (grp == 0) {
            partML[(size_t)slotId * 128 + rloc * 2]     = m_run;
            partML[(size_t)slotId * 128 + rloc * 2 + 1] = l;
        }
        u16* pa = partAcc + (size_t)slotId * 8192 + rloc * 128 + 4 * grp;
        #pragma unroll
        for (int ct = 0; ct < 8; ++ct) {
            uint2 pk;
            pk.x = pack2(acc_o[ct][0], acc_o[ct][1]);
            pk.y = pack2(acc_o[ct][2], acc_o[ct][3]);
            *reinterpret_cast<uint2*>(pa + ct * 16) = pk;
        }
    }
}

// ---------------- combine partial chunks (log2-unit m, bf16 partials) ----------------
__global__ __launch_bounds__(256) void attn_combine(
    const u16* __restrict__ partAcc, const float* __restrict__ partML,
    u16* __restrict__ outb)
{
    const int bid = blockIdx.x;                 // 384
    const int xcd = bid & 7, s2 = bid >> 3;     // 0..47
    const int h = xcd + 8 * (s2 / 24);
    const int qb = 8 + s2 % 24;
    int S, poff;
    if (qb < 16)      { S = 2; poff = (qb - 8) * 2; }
    else if (qb < 24) { S = 3; poff = 16 + (qb - 16) * 3; }
    else              { S = 4; poff = 40 + (qb - 24) * 4; }
    const int base = h * 72 + poff;
    const int tid = threadIdx.x;
    const int row = tid >> 2, seg = (tid & 3) * 32;

    float mv[4], lv[4];
    float m_g = -1e30f;
    #pragma unroll
    for (int s = 0; s < 4; ++s) {
        bool ok = (s < S);
        mv[s] = ok ? partML[(size_t)(base + s) * 128 + row * 2]     : -1e30f;
        lv[s] = ok ? partML[(size_t)(base + s) * 128 + row * 2 + 1] : 0.f;
        m_g = fmaxf(m_g, mv[s]);
    }
    float l_g = 0.f, wq[4];
    #pragma unroll
    for (int s = 0; s < 4; ++s) { wq[s] = exp2f(mv[s] - m_g); l_g += wq[s] * lv[s]; }
    float inv = 1.f / l_g;
    u16* orow = outb + (size_t)(qb * 64 + row) * 2048 + h * 128 + seg;
    #pragma unroll
    for (int i = 0; i < 8; ++i) {
        float o[4] = {0.f, 0.f, 0.f, 0.f};
        #pragma unroll
        for (int s = 0; s < 4; ++s) {
            if (s < S) {
                ushort4 a = *reinterpret_cast<const ushort4*>(
                    partAcc + (size_t)(base + s) * 8192 + row * 128 + seg + i * 4);
                o[0] += wq[s] * b2f(a.x); o[1] += wq[s] * b2f(a.y);
                o[2] += wq[s] * b2f(a.z); o[3] += wq[s] * b2f(a.w);
            }
        }
        uint2 pk;
        pk.x = pack2(o[0] * inv, o[1] * inv);
        pk.y = pack2(o[2] * inv, o[3] * inv);
        *reinterpret_cast<uint2*>(orow + i * 4) = pk;
    }
}

extern "C" void kernel_launch(void* const* d_in, const int* in_sizes, int n_in,
                              void* d_out, int out_size, void* d_ws, size_t ws_size,
                              hipStream_t stream)
{
    (void)in_sizes; (void)n_in; (void)out_size; (void)ws_size;
    const float* x         = (const float*)d_in[0];
    const float* Wq_down   = (const float*)d_in[1];
    const float* q_norm_w  = (const float*)d_in[2];
    const float* Wq_up     = (const float*)d_in[3];
    const float* Wkv_down  = (const float*)d_in[4];
    const float* kv_norm_w = (const float*)d_in[5];
    const float* Wkv_up    = (const float*)d_in[6];
    const float* Wo        = (const float*)d_in[7];
    float* out = (float*)d_out;

    char* p = (char*)d_ws;
    u16* BtF     = (u16*)p;   p += (size_t)2176 * 2048 * 2;   // fused [Wqd|Wkvd]^T
    u16* Wkvu_t  = (u16*)p;   p += (size_t)4096 * 512  * 2;
    u16* Wo_t    = (u16*)p;   p += (size_t)2048 * 2048 * 2;
    u16* qbuf    = (u16*)p;   p += (size_t)2048 * 3072 * 2;
    u16* ckvb    = (u16*)p;   p += (size_t)2048 * 512  * 2;
    u16* kvbf    = (u16*)p;   p += (size_t)2048 * 4096 * 2;
    u16* krotb   = (u16*)p;   p += (size_t)2048 * 64   * 2;
    // dead-by-attn pool: xb(8MB) | Wqu_t(9MB) | fC(16.5MB) | qdb(6MB)
    char* pool   = p;
    u16* xb      = (u16*)p;   p += (size_t)2048 * 2048 * 2;
    u16* Wqu_t   = (u16*)p;   p += (size_t)3072 * 1536 * 2;
    float* fC    = (float*)p; p += (size_t)2048 * 2112 * 4;
    u16* qdb     = (u16*)p;   p += (size_t)2048 * 1536 * 2;
    u16* attb    = (u16*)BtF;                     // aliases BtF (dead before attn)
    u16* partAcc = xb;                            // pool[0, 18.9MB)
    float* partML  = (float*)(partAcc + (size_t)1152 * 8192);   // ends 19.46MB
    u16* vtb     = (u16*)(pool + (size_t)20 * 1024 * 1024);     // pool[20, 28MB) in dead fC

    dim3 blk(256);
    prep_all<<<3136, blk, 0, stream>>>(x, xb, Wq_down, Wkv_down, BtF);

    gemm_down_fused<<<3232, blk, 0, stream>>>(xb, BtF, fC, Wq_up, Wkv_up, Wo,
                                              Wqu_t, Wkvu_t, Wo_t);
    rmsnorm2_bf16<<<2048, blk, 0, stream>>>(fC, q_norm_w, kv_norm_w, qdb, ckvb);
    gemm_dual<<<dim3(1792), blk, 0, stream>>>(qdb, Wqu_t, qbuf, ckvb, Wkvu_t, kvbf);
    rope_vtrans<<<3072, blk, 0, stream>>>(qbuf, fC + 2048, 2112, krotb, kvbf, vtb);

    attn_chunk<<<dim3(1280), blk, 0, stream>>>(qbuf, kvbf, krotb, vtb, attb, partAcc, partML);
    attn_combine<<<dim3(384), blk, 0, stream>>>(partAcc, partML, attb);

    gemm_wo<<<dim3(512), blk, 0, stream>>>(attb, Wo_t, out);
}

// Round 18
// 184.220 us; speedup vs baseline: 1.0221x; 1.0221x over previous
//
#include <hip/hip_runtime.h>
#include <hip/hip_bf16.h>
#include <cstddef>

#define H 16
#define DN 128
#define DR 64
#define DV 128
#define QLR 1536
#define KVLR 512
#define HID 2048
#define SLEN 2048
#define EPS 1e-6f
#define SCALE 0.08838834764831845f   /* 1/sqrt(128) */
#define QK_SCALE (0.08838834764831845f * 1.4426950408889634f)  /* SCALE * log2(e) */

typedef __attribute__((ext_vector_type(8))) short short8;
typedef __attribute__((ext_vector_type(4))) float f32x4;
typedef unsigned short u16;

__device__ __forceinline__ u16 f2bf(float f) {
    __hip_bfloat16 h = __float2bfloat16(f);
    return __builtin_bit_cast(u16, h);
}
__device__ __forceinline__ float b2f(u16 v) {
    return __bfloat162float(__builtin_bit_cast(__hip_bfloat16, v));
}
__device__ __forceinline__ unsigned pack2(float a, float b) {
    return (unsigned)f2bf(a) | ((unsigned)f2bf(b) << 16);
}

// ---------------- shared transpose-cast block: W f32 [K][N] tile -> Wt bf16 [Npad][K] ----------------
__device__ __forceinline__ void tcast_block(
    const float* __restrict__ W, u16* __restrict__ Wt,
    int K, int N, int nx, float scale, int b, float (*T)[65])
{
    const int tid = threadIdx.x;
    const int bx = b % nx, by = b / nx;
    const int n0 = bx * 64, k0 = by * 64;
    const bool inb = (n0 < N);
    {
        int r = tid >> 4, c4 = (tid & 15) * 4;
        #pragma unroll
        for (int rr = 0; rr < 4; ++rr) {
            int row = rr * 16 + r;
            float4 v = inb ? *reinterpret_cast<const float4*>(W + (size_t)(k0 + row) * N + n0 + c4)
                           : make_float4(0.f, 0.f, 0.f, 0.f);
            T[row][c4] = v.x * scale; T[row][c4 + 1] = v.y * scale;
            T[row][c4 + 2] = v.z * scale; T[row][c4 + 3] = v.w * scale;
        }
    }
    __syncthreads();
    {
        int n = tid >> 2, kq = (tid & 3) * 16;
        unsigned u[8];
        #pragma unroll
        for (int jj = 0; jj < 8; ++jj)
            u[jj] = pack2(T[kq + 2 * jj][n], T[kq + 2 * jj + 1][n]);
        u16* dst = Wt + (size_t)(n0 + n) * K + k0 + kq;
        *reinterpret_cast<uint4*>(dst)     = make_uint4(u[0], u[1], u[2], u[3]);
        *reinterpret_cast<uint4*>(dst + 8) = make_uint4(u[4], u[5], u[6], u[7]);
    }
}

// ---------------- prep: x cast (blocks 0..2047) + Wqd/Wkvd transpose-casts ----------------
__global__ __launch_bounds__(256) void prep_all(
    const float* __restrict__ x, u16* __restrict__ xb,
    const float* __restrict__ Wqd, const float* __restrict__ Wkvd,
    u16* __restrict__ BtF)
{
    const int tid = threadIdx.x;
    if (blockIdx.x < 2048) {
        size_t base = ((size_t)blockIdx.x * 256 + tid) * 8;
        float4 v0 = *reinterpret_cast<const float4*>(x + base);
        float4 v1 = *reinterpret_cast<const float4*>(x + base + 4);
        union { short8 s; unsigned u[4]; } p;
        p.u[0] = pack2(v0.x, v0.y); p.u[1] = pack2(v0.z, v0.w);
        p.u[2] = pack2(v1.x, v1.y); p.u[3] = pack2(v1.z, v1.w);
        *reinterpret_cast<short8*>(xb + base) = p.s;
        return;
    }
    __shared__ float T[64][65];
    int b = blockIdx.x - 2048;
    if (b < 768) tcast_block(Wqd, BtF, 2048, 1536, 24, 1.0f, b, T);
    else         tcast_block(Wkvd, BtF + (size_t)1536 * 2048, 2048, 576, 10, 1.0f, b - 768, T);
}

// ---------------- unified GEMM core: BM=64, BN=128, BK=64 (48KB double-buffered LDS) ----------------
__device__ __forceinline__ void stage6(const char* const* gb, const unsigned* srcOff,
                                       const int* ldsBase, u16* smemBuf, unsigned koff)
{
    #pragma unroll
    for (int j = 0; j < 6; ++j)
        __builtin_amdgcn_global_load_lds(
            (const __attribute__((address_space(1))) unsigned int*)(gb[j] + srcOff[j] + koff),
            (__attribute__((address_space(3))) unsigned int*)(smemBuf + ldsBase[j]),
            16, 0, 0);
}

template<bool BF16OUT>
__device__ __forceinline__ void gemm_core64(
    const u16* __restrict__ A, const u16* __restrict__ Bt, void* __restrict__ Cv,
    int N, int K, int m0, int n0, u16 (*smem)[12288])
{
    const int tid = threadIdx.x, lane = tid & 63, w = tid >> 6;
    const int colk = lane & 15, grp16 = (lane >> 4) * 16;
    const size_t Kb = (size_t)K * 2;

    const char* gb[6];
    unsigned srcOff[6];
    int ldsBase[6];
    #pragma unroll
    for (int j = 0; j < 6; ++j) {
        int c = w * 6 + j;
        bool isA = (c < 8);
        int cc = isA ? c : c - 8;
        int o = cc * 1024 + lane * 16;
        int u = o ^ (((o >> 7) & 7) << 4);
        int row = u >> 7, kbyte = u & 127;
        gb[j] = isA ? (const char*)A : (const char*)Bt;
        srcOff[j] = (unsigned)((size_t)(isA ? m0 + row : n0 + row) * Kb + kbyte);
        ldsBase[j] = isA ? cc * 512 : 4096 + cc * 512;
    }

    const int wc = w * 32;
    int aoff[8], boff[4];
    #pragma unroll
    for (int ks = 0; ks < 2; ++ks) {
        #pragma unroll
        for (int i = 0; i < 4; ++i) {
            int ra = i * 16 + colk;
            int oa = ra * 128 + ks * 64 + grp16;
            aoff[ks * 4 + i] = oa ^ ((ra & 7) << 4);
        }
        #pragma unroll
        for (int jj = 0; jj < 2; ++jj) {
            int rb = wc + jj * 16 + colk;
            int ob = rb * 128 + ks * 64 + grp16;
            boff[ks * 2 + jj] = (ob ^ ((rb & 7) << 4)) + 8192;
        }
    }

    f32x4 acc[4][2];
    #pragma unroll
    for (int i = 0; i < 4; ++i)
        #pragma unroll
        for (int j = 0; j < 2; ++j) acc[i][j] = (f32x4){0.f, 0.f, 0.f, 0.f};

    const int NT = K >> 6;
    stage6(gb, srcOff, ldsBase, &smem[0][0], 0);
    __syncthreads();
    int cur = 0;
    for (int t = 0; t < NT; ++t) {
        if (t + 1 < NT) stage6(gb, srcOff, ldsBase, &smem[cur ^ 1][0], (unsigned)(t + 1) * 128);
        const char* base = (const char*)&smem[cur][0];
        #pragma unroll
        for (int ks = 0; ks < 2; ++ks) {
            short8 af[4], bfr[2];
            #pragma unroll
            for (int i = 0; i < 4; ++i) af[i] = *reinterpret_cast<const short8*>(base + aoff[ks * 4 + i]);
            #pragma unroll
            for (int jj = 0; jj < 2; ++jj) bfr[jj] = *reinterpret_cast<const short8*>(base + boff[ks * 2 + jj]);
            __builtin_amdgcn_s_setprio(1);
            #pragma unroll
            for (int i = 0; i < 4; ++i)
                #pragma unroll
                for (int jj = 0; jj < 2; ++jj)
                    acc[i][jj] = __builtin_amdgcn_mfma_f32_16x16x32_bf16(af[i], bfr[jj], acc[i][jj], 0, 0, 0);
            __builtin_amdgcn_s_setprio(0);
        }
        __syncthreads();
        cur ^= 1;
    }

    #pragma unroll
    for (int i = 0; i < 4; ++i) {
        int grow0 = m0 + i * 16 + (grp16 >> 2);
        #pragma unroll
        for (int jj = 0; jj < 2; ++jj) {
            int gcol = n0 + wc + jj * 16 + colk;
            if (gcol < N) {
                #pragma unroll
                for (int r = 0; r < 4; ++r) {
                    float v2 = acc[i][jj][r];
                    if (BF16OUT) ((u16*)Cv)[(size_t)(grow0 + r) * N + gcol] = f2bf(v2);
                    else         ((float*)Cv)[(size_t)(grow0 + r) * N + gcol] = v2;
                }
            }
        }
    }
}

__device__ __forceinline__ void xcd_map(int orig, int nwg, int nby, int& bx, int& by)
{
    int xcd = orig & 7, o8 = orig >> 3;
    int qq = nwg >> 3, rr = nwg & 7;
    int v = (xcd < rr ? xcd * (qq + 1) : rr * (qq + 1) + (xcd - rr) * qq) + o8;
    bx = v / nby; by = v - bx * nby;
}

// down-GEMM (blocks 0..543) + Wqu/Wkvu/Wo transpose-casts (blocks 544..3231)
__global__ __launch_bounds__(256) void gemm_down_fused(
    const u16* __restrict__ xb, const u16* __restrict__ BtF, float* __restrict__ fC,
    const float* __restrict__ Wqu, const float* __restrict__ Wkvu, const float* __restrict__ Wo,
    u16* __restrict__ Wqu_t, u16* __restrict__ Wkvu_t, u16* __restrict__ Wo_t)
{
    __shared__ u16 smem[2][12288];   // 48 KB
    if (blockIdx.x < 544) {
        int bx, by;
        xcd_map(blockIdx.x, 544, 32, bx, by);
        gemm_core64<false>(xb, BtF, fC, 2112, 2048, by * 64, bx * 128, smem);
        return;
    }
    float (*T)[65] = reinterpret_cast<float(*)[65]>(&smem[0][0]);
    int b = blockIdx.x - 544;
    if (b < 1152)      tcast_block(Wqu,  Wqu_t,  1536, 3072, 48, QK_SCALE, b, T);
    else if (b < 1664) tcast_block(Wkvu, Wkvu_t, 512,  4096, 64, 1.0f, b - 1152, T);
    else               tcast_block(Wo,   Wo_t,   2048, 2048, 32, 1.0f, b - 1664, T);
}

// q_up (blocks 0..767) + kv_up (blocks 768..1791) in one launch
__global__ __launch_bounds__(256) void gemm_dual(
    const u16* __restrict__ Aq, const u16* __restrict__ Bq, u16* __restrict__ Cq,
    const u16* __restrict__ Ak, const u16* __restrict__ Bk, u16* __restrict__ Ck)
{
    __shared__ u16 smem[2][12288];
    int b = blockIdx.x;
    const u16 *A, *Bt; u16* C; int N, K, nwg;
    if (b < 768) { A = Aq; Bt = Bq; C = Cq; N = 3072; K = 1536; nwg = 768; }
    else { b -= 768; A = Ak; Bt = Bk; C = Ck; N = 4096; K = 512; nwg = 1024; }
    int bx, by;
    xcd_map(b, nwg, 32, bx, by);
    gemm_core64<true>(A, Bt, C, N, K, by * 64, bx * 128, smem);
}

// Wo GEMM: 512 blocks (16 x 32), fp32 out
__global__ __launch_bounds__(256) void gemm_wo(
    const u16* __restrict__ A, const u16* __restrict__ Bt, float* __restrict__ C)
{
    __shared__ u16 smem[2][12288];
    int bx, by;
    xcd_map(blockIdx.x, 512, 32, bx, by);
    gemm_core64<false>(A, Bt, C, 2048, 2048, by * 64, bx * 128, smem);
}

// ---------------- fused double RMSNorm: fC rows -> qdb (1536) + ckvb (512) ----------------
__global__ __launch_bounds__(256) void rmsnorm2_bf16(
    const float* __restrict__ fC, const float* __restrict__ qw,
    const float* __restrict__ kvw, u16* __restrict__ qdb, u16* __restrict__ ckvb)
{
    const int row = blockIdx.x, tid = threadIdx.x;
    const float* p = fC + (size_t)row * 2112;
    float ssq = 0.f, ssk = 0.f;
    for (int i = tid * 4; i < 1536; i += 1024) {
        float4 v = *reinterpret_cast<const float4*>(p + i);
        ssq += v.x * v.x + v.y * v.y + v.z * v.z + v.w * v.w;
    }
    if (tid < 128) {
        float4 v = *reinterpret_cast<const float4*>(p + 1536 + tid * 4);
        ssk = v.x * v.x + v.y * v.y + v.z * v.z + v.w * v.w;
    }
    __shared__ float wsq[4], wsk[4];
    int lane = tid & 63, wv = tid >> 6;
    #pragma unroll
    for (int off = 32; off; off >>= 1) {
        ssq += __shfl_down(ssq, off);
        ssk += __shfl_down(ssk, off);
    }
    if (lane == 0) { wsq[wv] = ssq; wsk[wv] = ssk; }
    __syncthreads();
    if (tid == 0) {
        wsq[0] = rsqrtf((wsq[0] + wsq[1] + wsq[2] + wsq[3]) / 1536.f + EPS);
        wsk[0] = rsqrtf((wsk[0] + wsk[1] + wsk[2] + wsk[3]) / 512.f + EPS);
    }
    __syncthreads();
    float scq = wsq[0], sck = wsk[0];
    for (int i = tid * 4; i < 1536; i += 1024) {
        float4 v = *reinterpret_cast<const float4*>(p + i);
        float4 g = *reinterpret_cast<const float4*>(qw + i);
        *reinterpret_cast<uint2*>(qdb + (size_t)row * 1536 + i) =
            make_uint2(pack2(v.x * scq * g.x, v.y * scq * g.y),
                       pack2(v.z * scq * g.z, v.w * scq * g.w));
    }
    if (tid < 128) {
        int i = tid * 4;
        float4 v = *reinterpret_cast<const float4*>(p + 1536 + i);
        float4 g = *reinterpret_cast<const float4*>(kvw + i);
        *reinterpret_cast<uint2*>(ckvb + (size_t)row * 512 + i) =
            make_uint2(pack2(v.x * sck * g.x, v.y * sck * g.y),
                       pack2(v.z * sck * g.z, v.w * sck * g.w));
    }
}

// ---------------- merged: RoPE (blocks 0..2047) + V transpose (blocks 2048..3071) ----------------
__global__ __launch_bounds__(256) void rope_vtrans(
    u16* __restrict__ q, const float* __restrict__ krsrc, int krStride,
    u16* __restrict__ krot, const u16* __restrict__ kvbf, u16* __restrict__ vtb)
{
    const int tid = threadIdx.x;
    if (blockIdx.x < 2048) {
        const int s = blockIdx.x;
        __shared__ float cs[32], sn[32];
        if (tid < 32) {
            float inv = powf(10000.0f, -(float)tid / 32.0f);
            float ang = (float)s * inv;
            cs[tid] = cosf(ang); sn[tid] = sinf(ang);
        }
        __syncthreads();
        float ev[2], ov[2]; int hh[2], ii[2];
        #pragma unroll
        for (int it = 0; it < 2; ++it) {
            int pidx = tid + it * 256;
            int h = pidx >> 5, i = pidx & 31;
            hh[it] = h; ii[it] = i;
            const u16* base = q + (size_t)s * 3072 + h * 192 + 128;
            ev[it] = b2f(base[2 * i]); ov[it] = b2f(base[2 * i + 1]);
        }
        __syncthreads();
        #pragma unroll
        for (int it = 0; it < 2; ++it) {
            int h = hh[it], i = ii[it];
            u16* base = q + (size_t)s * 3072 + h * 192 + 128;
            base[i]      = f2bf(ev[it] * cs[i] - ov[it] * sn[i]);
            base[32 + i] = f2bf(ov[it] * cs[i] + ev[it] * sn[i]);
        }
        if (tid < 32) {
            int i = tid;
            float e = krsrc[(size_t)s * krStride + 2 * i];
            float o = krsrc[(size_t)s * krStride + 2 * i + 1];
            krot[(size_t)s * 64 + i]      = f2bf(e * cs[i] - o * sn[i]);
            krot[(size_t)s * 64 + 32 + i] = f2bf(o * cs[i] + e * sn[i]);
        }
        return;
    }
    const int bid = blockIdx.x - 2048;     // 1024 = 16 h x 32 s-tiles x 2 d-tiles
    const int h = bid & 15, rem = bid >> 4;
    const int st = rem & 31, dt = rem >> 5;
    __shared__ u16 T[64][72];
    #pragma unroll
    for (int it = 0; it < 2; ++it) {
        int c = it * 256 + tid;
        int r = c >> 3, c8 = (c & 7) * 8;
        short8 v = *reinterpret_cast<const short8*>(
            kvbf + ((size_t)(st * 64 + r) * 16 + h) * 256 + 128 + dt * 64 + c8);
        *reinterpret_cast<short8*>(&T[r][c8]) = v;
    }
    __syncthreads();
    #pragma unroll
    for (int it = 0; it < 2; ++it) {
        int c = it * 256 + tid;
        int d = c >> 3, s8 = (c & 7) * 8;
        union { short8 s; u16 e[8]; } o;
        #pragma unroll
        for (int j = 0; j < 8; ++j) o.e[j] = T[s8 + j][d];
        *reinterpret_cast<short8*>(
            vtb + ((size_t)(h * 128 + dt * 64 + d)) * 2048 + st * 64 + s8) = o.s;
    }
}

// ---------------- split-K flash attention: KB=32, gload_lds double-buffer, 1 barrier/tile ----------------
// 1280 blocks, big-chunks-first XCD-mapped; 256 thr = 4 waves; 64 q-rows/block.
// Per tile: STAGE(next buf via global_load_lds, 5 per thread) -> compute current -> barrier.
__global__ __launch_bounds__(256, 2) void attn_chunk(
    const u16* __restrict__ qbf,   // [S][H][192]
    const u16* __restrict__ kvbf,  // [S][H][256]  (k_nope | v)
    const u16* __restrict__ krot,  // [S][64]
    const u16* __restrict__ vtb,   // [H][128][2048]  V^T
    u16* __restrict__ outb,        // [S][2048]
    u16* __restrict__ partAcc,     // [1152][64][128] bf16
    float* __restrict__ partML)    // [1152][64][2]
{
    const int bid = blockIdx.x;
    const int xcd = bid & 7, slot = bid >> 3;       // slot 0..159
    const int h = xcd + 8 * (slot & 1);             // interleave heads
    const int r80 = 79 - (slot >> 1);               // big chunks first
    int qb, ch, S, poff;
    if (r80 < 8)       { qb = r80;                 ch = 0;      S = 1; poff = 0; }
    else if (r80 < 24) { int u = r80 - 8;  qb = 8 + (u >> 1);  ch = u & 1; S = 2; poff = (qb - 8) * 2 + ch; }
    else if (r80 < 48) { int u = r80 - 24; qb = 16 + u / 3;    ch = u % 3; S = 3; poff = 16 + (qb - 16) * 3 + ch; }
    else               { int u = r80 - 48; qb = 24 + (u >> 2); ch = u & 3; S = 4; poff = 40 + (qb - 24) * 4 + ch; }
    const int s0 = qb * 64;
    const int nt32 = 2 * qb + 2;                    // 32-key tiles total
    const int t0 = ch * 16;
    const int t1 = (t0 + 16 < nt32) ? (t0 + 16) : nt32;
    const int slotId = h * 72 + poff;
    const int tid = threadIdx.x, lane = tid & 63, w = tid >> 6;
    const int colk = lane & 15, grp = lane >> 4, g8 = grp * 8;

    // per buffer: [Ks 32x192 u16 = 6144][Vt 128x32 u16 = 4096] = 10240 u16 (20KB)
    __shared__ u16 smem[2][10240];

    const int qg = s0 + w * 16 + colk;

    short8 qreg[6];
    {
        const u16* qp = qbf + ((size_t)qg * H + h) * 192;
        #pragma unroll
        for (int ks = 0; ks < 6; ++ks)
            qreg[ks] = *reinterpret_cast<const short8*>(qp + ks * 32 + g8);
    }

    // staging: 20 chunks of 1KB (Ks 0..11, Vt 12..19); wave w owns chunks 5w..5w+4.
    const char* gbase[5];
    unsigned curOff[5], strideB[5];
    int ldsOff[5];
    #pragma unroll
    for (int j = 0; j < 5; ++j) {
        int c = w * 5 + j;
        if (c < 12) {
            int o = c * 1024 + lane * 16;           // byte within Ks region
            int row = o / 384, rem = o % 384, s = rem >> 4;
            int kslot = (s & 24) | ((s ^ row) & 7);
            if (kslot < 16) {
                gbase[j] = (const char*)(kvbf + h * 256);
                curOff[j] = (unsigned)((row * 4096 + kslot * 8) * 2);
                strideB[j] = 32 * 4096 * 2;
            } else {
                gbase[j] = (const char*)krot;
                curOff[j] = (unsigned)((row * 64 + (kslot - 16) * 8) * 2);
                strideB[j] = 32 * 64 * 2;
            }
            ldsOff[j] = c * 512;
        } else {
            int cc = c - 12;
            int o = cc * 1024 + lane * 16;          // byte within Vt region
            int row = o >> 6, s = (o & 63) >> 4;    // row = d (0..127), 4 slots
            int vks = (s ^ row ^ (row >> 2)) & 3;
            gbase[j] = (const char*)(vtb + (size_t)h * 128 * 2048);
            curOff[j] = (unsigned)((row * 2048 + vks * 8) * 2);
            strideB[j] = 32 * 2;
            ldsOff[j] = 6144 + cc * 512;
        }
        curOff[j] += (unsigned)t0 * strideB[j];
    }

    float m_run = -1e30f, l_run = 0.f;
    f32x4 acc_o[8];
    #pragma unroll
    for (int i = 0; i < 8; ++i) acc_o[i] = (f32x4){0.f, 0.f, 0.f, 0.f};

    const int srcA = colk + ((grp & 1) << 5);
    const int srcB = srcA + 16;
    const bool hiSel = (grp >> 1) != 0;

    // prologue: stage tile t0 into buffer 0
    #pragma unroll
    for (int j = 0; j < 5; ++j) {
        __builtin_amdgcn_global_load_lds(
            (const __attribute__((address_space(1))) unsigned int*)(gbase[j] + curOff[j]),
            (__attribute__((address_space(3))) unsigned int*)(&smem[0][0] + ldsOff[j]),
            16, 0, 0);
        curOff[j] += strideB[j];
    }
    __syncthreads();

    int buf = 0;
    for (int t = t0; t < t1; ++t) {
        if (t + 1 < t1) {
            u16* dst = &smem[buf ^ 1][0];
            #pragma unroll
            for (int j = 0; j < 5; ++j) {
                __builtin_amdgcn_global_load_lds(
                    (const __attribute__((address_space(1))) unsigned int*)(gbase[j] + curOff[j]),
                    (__attribute__((address_space(3))) unsigned int*)(dst + ldsOff[j]),
                    16, 0, 0);
                curOff[j] += strideB[j];
            }
        }
        const u16* KsB = &smem[buf][0];
        const u16* VtB = &smem[buf][6144];

        // swapped QK^T: sacc[ct][r] = S[key = t*32 + ct*16 + 4*grp + r][q = colk]
        f32x4 sacc[2];
        sacc[0] = (f32x4){0.f, 0.f, 0.f, 0.f};
        sacc[1] = (f32x4){0.f, 0.f, 0.f, 0.f};
        __builtin_amdgcn_s_setprio(1);
        #pragma unroll
        for (int ks = 0; ks < 6; ++ks) {
            #pragma unroll
            for (int ct = 0; ct < 2; ++ct) {
                int key = ct * 16 + colk;
                int slotIdx = ks * 4 + grp;
                int sl = (slotIdx & 24) | ((slotIdx ^ key) & 7);
                short8 kf = *reinterpret_cast<const short8*>(&KsB[key * 192 + sl * 8]);
                sacc[ct] = __builtin_amdgcn_mfma_f32_16x16x32_bf16(kf, qreg[ks], sacc[ct], 0, 0, 0);
            }
        }
        __builtin_amdgcn_s_setprio(0);

        // causal mask (only tiles overlapping the diagonal)
        if (t >= 2 * qb) {
            #pragma unroll
            for (int ct = 0; ct < 2; ++ct) {
                int keyb = t * 32 + ct * 16 + 4 * grp;
                #pragma unroll
                for (int r = 0; r < 4; ++r)
                    if (keyb + r > qg) sacc[ct][r] = -1e30f;
            }
        }

        // in-lane row max over 8, gated rescale
        float lmax = fmaxf(fmaxf(fmaxf(sacc[0][0], sacc[0][1]), fmaxf(sacc[0][2], sacc[0][3])),
                           fmaxf(fmaxf(sacc[1][0], sacc[1][1]), fmaxf(sacc[1][2], sacc[1][3])));
        bool need = lmax > m_run + 11.5f;
        if (__any((int)need)) {
            float mx = fmaxf(m_run, lmax);
            mx = fmaxf(mx, __shfl_xor(mx, 16));
            mx = fmaxf(mx, __shfl_xor(mx, 32));
            float f = exp2f(m_run - mx);
            m_run = mx;
            l_run *= f;
            #pragma unroll
            for (int i = 0; i < 8; ++i) {
                acc_o[i][0] *= f; acc_o[i][1] *= f;
                acc_o[i][2] *= f; acc_o[i][3] *= f;
            }
        }

        // P = exp2(S - m), packed bf16 pairs
        unsigned pku[4];
        float psum = 0.f;
        #pragma unroll
        for (int ct = 0; ct < 2; ++ct) {
            float p0 = exp2f(sacc[ct][0] - m_run);
            float p1 = exp2f(sacc[ct][1] - m_run);
            float p2 = exp2f(sacc[ct][2] - m_run);
            float p3 = exp2f(sacc[ct][3] - m_run);
            psum += (p0 + p1) + (p2 + p3);
            pku[ct * 2]     = pack2(p0, p1);
            pku[ct * 2 + 1] = pack2(p2, p3);
        }
        l_run += psum;

        // swapped PV: b-frag of P^T via 4-lane-group shuffles
        unsigned a0 = __shfl(pku[0], srcA);
        unsigned a1 = __shfl(pku[1], srcA);
        unsigned a2 = __shfl(pku[0], srcB);
        unsigned a3 = __shfl(pku[1], srcB);
        unsigned b0 = __shfl(pku[2], srcA);
        unsigned b1 = __shfl(pku[3], srcA);
        unsigned b2 = __shfl(pku[2], srcB);
        unsigned b3 = __shfl(pku[3], srcB);
        union { short8 s; unsigned u[4]; } bq;
        bq.u[0] = hiSel ? b0 : a0;
        bq.u[1] = hiSel ? b1 : a1;
        bq.u[2] = hiSel ? b2 : a2;
        bq.u[3] = hiSel ? b3 : a3;
        __builtin_amdgcn_s_setprio(1);
        #pragma unroll
        for (int ct = 0; ct < 8; ++ct) {
            int cc = ct * 16 + colk;
            int vsl = (grp ^ cc ^ (cc >> 2)) & 3;
            short8 vb = *reinterpret_cast<const short8*>(&VtB[cc * 32 + vsl * 8]);
            acc_o[ct] = __builtin_amdgcn_mfma_f32_16x16x32_bf16(vb, bq.s, acc_o[ct], 0, 0, 0);
        }
        __builtin_amdgcn_s_setprio(0);

        __syncthreads();   // drains next tile's loads; all waves done reading buf
        buf ^= 1;
    }

    float l = l_run;
    l += __shfl_xor(l, 16);
    l += __shfl_xor(l, 32);
    const int rloc = w * 16 + colk;
    if (S == 1) {
        float invl = 1.0f / l;
        u16* orow = outb + (size_t)qg * 2048 + h * 128 + 4 * grp;
        #pragma unroll
        for (int ct = 0; ct < 8; ++ct) {
            uint2 pk;
            pk.x = pack2(acc_o[ct][0] * invl, acc_o[ct][1] * invl);
            pk.y = pack2(acc_o[ct][2] * invl, acc_o[ct][3] * invl);
            *reinterpret_cast<uint2*>(orow + ct * 16) = pk;
        }
    } else {
        if (grp == 0) {
            partML[(size_t)slotId * 128 + rloc * 2]     = m_run;
            partML[(size_t)slotId * 128 + rloc * 2 + 1] = l;
        }
        u16* pa = partAcc + (size_t)slotId * 8192 + rloc * 128 + 4 * grp;
        #pragma unroll
        for (int ct = 0; ct < 8; ++ct) {
            uint2 pk;
            pk.x = pack2(acc_o[ct][0], acc_o[ct][1]);
            pk.y = pack2(acc_o[ct][2], acc_o[ct][3]);
            *reinterpret_cast<uint2*>(pa + ct * 16) = pk;
        }
    }
}

// ---------------- combine partial chunks (log2-unit m, bf16 partials) ----------------
__global__ __launch_bounds__(256) void attn_combine(
    const u16* __restrict__ partAcc, const float* __restrict__ partML,
    u16* __restrict__ outb)
{
    const int bid = blockIdx.x;                 // 384
    const int xcd = bid & 7, s2 = bid >> 3;     // 0..47
    const int h = xcd + 8 * (s2 / 24);
    const int qb = 8 + s2 % 24;
    int S, poff;
    if (qb < 16)      { S = 2; poff = (qb - 8) * 2; }
    else if (qb < 24) { S = 3; poff = 16 + (qb - 16) * 3; }
    else              { S = 4; poff = 40 + (qb - 24) * 4; }
    const int base = h * 72 + poff;
    const int tid = threadIdx.x;
    const int row = tid >> 2, seg = (tid & 3) * 32;

    float mv[4], lv[4];
    float m_g = -1e30f;
    #pragma unroll
    for (int s = 0; s < 4; ++s) {
        bool ok = (s < S);
        mv[s] = ok ? partML[(size_t)(base + s) * 128 + row * 2]     : -1e30f;
        lv[s] = ok ? partML[(size_t)(base + s) * 128 + row * 2 + 1] : 0.f;
        m_g = fmaxf(m_g, mv[s]);
    }
    float l_g = 0.f, wq[4];
    #pragma unroll
    for (int s = 0; s < 4; ++s) { wq[s] = exp2f(mv[s] - m_g); l_g += wq[s] * lv[s]; }
    float inv = 1.f / l_g;
    u16* orow = outb + (size_t)(qb * 64 + row) * 2048 + h * 128 + seg;
    #pragma unroll
    for (int i = 0; i < 8; ++i) {
        float o[4] = {0.f, 0.f, 0.f, 0.f};
        #pragma unroll
        for (int s = 0; s < 4; ++s) {
            if (s < S) {
                ushort4 a = *reinterpret_cast<const ushort4*>(
                    partAcc + (size_t)(base + s) * 8192 + row * 128 + seg + i * 4);
                o[0] += wq[s] * b2f(a.x); o[1] += wq[s] * b2f(a.y);
                o[2] += wq[s] * b2f(a.z); o[3] += wq[s] * b2f(a.w);
            }
        }
        uint2 pk;
        pk.x = pack2(o[0] * inv, o[1] * inv);
        pk.y = pack2(o[2] * inv, o[3] * inv);
        *reinterpret_cast<uint2*>(orow + i * 4) = pk;
    }
}

extern "C" void kernel_launch(void* const* d_in, const int* in_sizes, int n_in,
                              void* d_out, int out_size, void* d_ws, size_t ws_size,
                              hipStream_t stream)
{
    (void)in_sizes; (void)n_in; (void)out_size; (void)ws_size;
    const float* x         = (const float*)d_in[0];
    const float* Wq_down   = (const float*)d_in[1];
    const float* q_norm_w  = (const float*)d_in[2];
    const float* Wq_up     = (const float*)d_in[3];
    const float* Wkv_down  = (const float*)d_in[4];
    const float* kv_norm_w = (const float*)d_in[5];
    const float* Wkv_up    = (const float*)d_in[6];
    const float* Wo        = (const float*)d_in[7];
    float* out = (float*)d_out;

    char* p = (char*)d_ws;
    u16* BtF     = (u16*)p;   p += (size_t)2176 * 2048 * 2;   // fused [Wqd|Wkvd]^T
    u16* Wkvu_t  = (u16*)p;   p += (size_t)4096 * 512  * 2;
    u16* Wo_t    = (u16*)p;   p += (size_t)2048 * 2048 * 2;
    u16* qbuf    = (u16*)p;   p += (size_t)2048 * 3072 * 2;
    u16* ckvb    = (u16*)p;   p += (size_t)2048 * 512  * 2;
    u16* kvbf    = (u16*)p;   p += (size_t)2048 * 4096 * 2;
    u16* krotb   = (u16*)p;   p += (size_t)2048 * 64   * 2;
    // dead-by-attn pool: xb(8MB) | Wqu_t(9MB) | fC(16.5MB) | qdb(6MB)
    char* pool   = p;
    u16* xb      = (u16*)p;   p += (size_t)2048 * 2048 * 2;
    u16* Wqu_t   = (u16*)p;   p += (size_t)3072 * 1536 * 2;
    float* fC    = (float*)p; p += (size_t)2048 * 2112 * 4;
    u16* qdb     = (u16*)p;   p += (size_t)2048 * 1536 * 2;
    u16* attb    = (u16*)BtF;                     // aliases BtF (dead before attn)
    u16* partAcc = xb;                            // pool[0, 18.9MB)
    float* partML  = (float*)(partAcc + (size_t)1152 * 8192);   // ends 19.46MB
    u16* vtb     = (u16*)(pool + (size_t)20 * 1024 * 1024);     // pool[20, 28MB) in dead fC

    dim3 blk(256);
    prep_all<<<3136, blk, 0, stream>>>(x, xb, Wq_down, Wkv_down, BtF);

    gemm_down_fused<<<3232, blk, 0, stream>>>(xb, BtF, fC, Wq_up, Wkv_up, Wo,
                                              Wqu_t, Wkvu_t, Wo_t);
    rmsnorm2_bf16<<<2048, blk, 0, stream>>>(fC, q_norm_w, kv_norm_w, qdb, ckvb);
    gemm_dual<<<dim3(1792), blk, 0, stream>>>(qdb, Wqu_t, qbuf, ckvb, Wkvu_t, kvbf);
    rope_vtrans<<<3072, blk, 0, stream>>>(qbuf, fC + 2048, 2112, krotb, kvbf, vtb);

    attn_chunk<<<dim3(1280), blk, 0, stream>>>(qbuf, kvbf, krotb, vtb, attb, partAcc, partML);
    attn_combine<<<dim3(384), blk, 0, stream>>>(partAcc, partML, attb);

    gemm_wo<<<dim3(512), blk, 0, stream>>>(attb, Wo_t, out);
}